// Round 12
// baseline (170.957 us; speedup 1.0000x reference)
//
#include <hip/hip_runtime.h>
#include <hip/hip_bf16.h>
#include <math.h>

#define NPTS 2097152
#define IMGW 1024
#define IMGH 1024

typedef __attribute__((ext_vector_type(8))) short bf16x8;   // 8 bf16 = 4 VGPR
typedef __attribute__((ext_vector_type(4))) float f32x4;
typedef __attribute__((ext_vector_type(2))) float f32x2;
typedef __attribute__((ext_vector_type(2))) unsigned int u32x2;
typedef __attribute__((ext_vector_type(4))) unsigned int u32x4;

// ws layout (bytes):
//   [0,      34816)  weight frags (17408 ushorts):
//       [0, 12288)     WB: fused [Wf(48xk) ; W0(10xk) ; bias row 58] -> K=64, N=192.
//                      12 ntiles x 2 ksteps x 64 lanes x 8 bf16 fragments.
//                      ntile 0..3 = gamma, 4..7 = beta, 8..11 = h0 cols.
//                      Row 58 holds bff/b0 (feature 58 == 1.0 in phase 1).
//       [12288,16384)  W1: 4 ntiles x 2 ksteps x 64 x 8
//       [16384,17408)  W2: 1 ntile  x 2 ksteps x 64 x 8  (cols 4..15 zero)
//   [34816, 100352)  tX: f32[1024][16]  = Wp_x @ spiral_x(px)          (64 KB)
//   [100352,165888)  tY: f32[1024][16]  = Wp_y @ spiral_y(py) + bp     (64 KB)
//   [165888,174080)  tS: float2[1024]   = {sin(2pi p/1024), sin(4pi p/1024)}
// Requires ws_size >= 174080 bytes.
#define TX_OFF 34816
#define TY_OFF 100352
#define TS_OFF 165888
#define PREP_ITEMS 51200   // 17408 + 16384 + 16384 + 1024

__device__ __forceinline__ unsigned short f2bf(float f) {
    __hip_bfloat16 h = __float2bfloat16(f);          // RTNE; pairs fuse to v_cvt_pk_bf16_f32
    return __builtin_bit_cast(unsigned short, h);
}
__device__ __forceinline__ unsigned pk2(float a, float b) {
    return (unsigned)f2bf(a) | ((unsigned)f2bf(b) << 16);
}
__device__ __forceinline__ f32x2 mk2(float a, float b) { f32x2 r; r.x = a; r.y = b; return r; }

__device__ __forceinline__ float s2pi(float r) { r = r - floorf(r); return __builtin_amdgcn_sinf(r); }
__device__ __forceinline__ float c2pi(float r) { r = r + 0.25f; r = r - floorf(r); return __builtin_amdgcn_sinf(r); }

__global__ __launch_bounds__(256) void prepack(
    const float* __restrict__ Wf, const float* __restrict__ W0,
    const float* __restrict__ W1, const float* __restrict__ W2,
    const float* __restrict__ Wp, const float* __restrict__ bp,
    const float* __restrict__ bff, const float* __restrict__ b0,
    unsigned short* __restrict__ ws)
{
    int idx = blockIdx.x * 256 + threadIdx.x;
    if (idx < 17408) {                           // ---- weight fragments ----
        float val = 0.f;
        if (idx < 12288) {                       // fused Wf|W0 -> B frags (K=64)
            int e = idx, i = e & 7, l = (e >> 3) & 63, ks = (e >> 9) & 1, n = e >> 10;
            int k = ks * 32 + (l >> 4) * 8 + i;
            int c16 = l & 15;
            if (n < 8) {
                if (k < 48) val = Wf[k * 128 + n * 16 + c16];
                else if (k == 58) val = bff[n * 16 + c16];           // bias row
            } else {
                if (k >= 48 && k < 58) val = W0[(k - 48) * 64 + (n - 8) * 16 + c16];
                else if (k == 58) val = b0[(n - 8) * 16 + c16];      // bias row
            }
        } else if (idx < 16384) {                // W1 (64x64)
            int e = idx - 12288, i = e & 7, l = (e >> 3) & 63, ks = (e >> 9) & 1, n = e >> 10;
            int k = ks * 32 + (l >> 4) * 8 + i;
            val = W1[k * 64 + n * 16 + (l & 15)];
        } else {                                 // W2 (64x4, N padded to 16)
            int e = idx - 16384, i = e & 7, l = (e >> 3) & 63, ks = (e >> 9) & 1;
            int k = ks * 32 + (l >> 4) * 8 + i;
            int c = l & 15;
            if (c < 4) val = W2[k * 4 + c];
        }
        ws[idx] = f2bf(val);
    } else if (idx < 33792) {                    // ---- tX ----
        int e = idx - 17408, p = e >> 4, j = e & 15;
        float xf = (float)p * (1.0f / IMGW);
        float s[6] = { s2pi(xf), c2pi(xf), s2pi(2.f * xf), c2pi(2.f * xf), s2pi(3.f * xf), c2pi(3.f * xf) };
        float a = 0.f;
        #pragma unroll
        for (int k = 0; k < 6; ++k) a = fmaf(s[k], Wp[k * 16 + j], a);
        ((float*)((char*)ws + TX_OFF))[p * 16 + j] = a;
    } else if (idx < 50176) {                    // ---- tY (bias folded) ----
        int e = idx - 33792, p = e >> 4, j = e & 15;
        float yf = (float)p * (1.0f / IMGH);
        float s[6] = { s2pi(yf), c2pi(yf), s2pi(2.f * yf), c2pi(2.f * yf), s2pi(3.f * yf), c2pi(3.f * yf) };
        float a = bp[j];
        #pragma unroll
        for (int k = 0; k < 6; ++k) a = fmaf(s[k], Wp[(6 + k) * 16 + j], a);
        ((float*)((char*)ws + TY_OFF))[p * 16 + j] = a;
    } else if (idx < 51200) {                    // ---- tS ----
        int p = idx - 50176;
        float xf = (float)p * (1.0f / IMGW);
        float2 v; v.x = s2pi(xf); v.y = s2pi(2.f * xf);
        ((float2*)((char*)ws + TS_OFF))[p] = v;
    }
}

// R10's tanh-form GELU (harness-proven): 5 VALU + 2 TRANS per element.
//   x2 = x*x;  m = fma(x2, -K2, -K);  e = exp2(x*m);  s = rcp(1+e);  out = x*s
// K = 2*sqrt(2/pi)*log2(e) = 2.30220818, K2 = K*0.044715 = 0.10294324.
// Max deviation from exact erf-GELU ~4e-4, well under the 1.41e-2 threshold.
__device__ __forceinline__ f32x2 gelu2(f32x2 x) {
    const f32x2 x2 = x * x;
    f32x2 m = __builtin_elementwise_fma(x2, mk2(-0.10294324f, -0.10294324f),
                                        mk2(-2.30220818f, -2.30220818f));
    f32x2 a = x * m;
    f32x2 e; e.x = __builtin_amdgcn_exp2f(a.x); e.y = __builtin_amdgcn_exp2f(a.y);
    f32x2 s; s.x = __builtin_amdgcn_rcpf(1.f + e.x); s.y = __builtin_amdgcn_rcpf(1.f + e.y);
    return x * s;
}

#define MFMA(a, b, c) __builtin_amdgcn_mfma_f32_16x16x32_bf16((a), (b), (c), 0, 0, 0)

// Compiler-only reorder fence (R7: wave-private LDS + in-order DS pipe ->
// no hardware lgkmcnt drains needed; compiler auto-inserts data-dep waits).
#define CFENCE() asm volatile("" ::: "memory")

// TRANSPOSED MFMA structure (R9, harness-proven): W as A-operand, feat/h as
// B-operand -> D^T: lane holds point=cl, hidden=lg*4+r. One ds_write_b64 per
// (n,mt); GEMM3 stores one dwordx4 per point from lg==0 lanes.
// LDS: featL = 256 rows x 64 bf16 (XOR-swizzled 16B granules) = 32 KB; hT
// tiles alias the wave's own featL rows (dead after A-fragment preload).
// Wave-private everywhere -> NO __syncthreads.
//
// R12 — second occupancy step: R11 proved the unified-RF theory ((256,4) with
// slim live set -> 41% occupancy, no spill, -10.6% time, marginal return on
// occupancy still positive). LDS 32KB/block -> 5 blocks/CU fits 160KB exactly;
// (256,5) caps total regs at ~102/wave (arch 60 + ~12 accs fits).
// Spill tripwire: WRITE_SIZE must stay exactly 32768 KB; revert to (256,4)
// if it balloons or occupancy drops.
__global__ __launch_bounds__(256, 5) void vfx_fwd(
    const int* __restrict__ rawpos, const float* __restrict__ control,
    const float* __restrict__ latent,
    const float* __restrict__ Wc, const float* __restrict__ bc,
    const float* __restrict__ Wt, const float* __restrict__ bt,
    const float* __restrict__ b1, const float* __restrict__ b2,
    const unsigned short* __restrict__ ws, float* __restrict__ out)
{
    __shared__ __align__(16) unsigned char smem[32768];
    const int tid = threadIdx.x;
    const int i = blockIdx.x * 256 + tid;
    const unsigned char* wsb = (const unsigned char*)ws;

    // ============ phase 1: per-point features -> LDS (proven code) ====
    {
        const int px = rawpos[2 * i], py = rawpos[2 * i + 1];
        const float c0 = control[2 * i], c1 = control[2 * i + 1];
        const float4 lat = *reinterpret_cast<const float4*>(latent + 4 * (py * IMGW + px));
        const int pxc = min(max(px, 0), IMGW - 1), pyc = min(max(py, 0), IMGH - 1);
        const float xf = (float)pxc * (1.0f / IMGW);
        const float yf = (float)pyc * (1.0f / IMGH);
        const float2 sxv = ((const float2*)(wsb + TS_OFF))[pxc];
        const float2 syv = ((const float2*)(wsb + TS_OFF))[pyc];

        unsigned char* myrow = &smem[tid * 128];
        const int sw = tid & 7;

        {   // control feat (2->16) -> groups 0,1
            const f32x2* Wc2 = (const f32x2*)Wc;
            const f32x2* bc2 = (const f32x2*)bc;
            const f32x2 c0s = mk2(c0, c0), c1s = mk2(c1, c1);
            f32x2 cf[8];
            #pragma unroll
            for (int jp = 0; jp < 8; ++jp) {
                f32x2 a = __builtin_elementwise_fma(c1s, Wc2[8 + jp], bc2[jp]);
                a = __builtin_elementwise_fma(c0s, Wc2[jp], a);
                cf[jp] = __builtin_elementwise_max(a, mk2(0.f, 0.f));
            }
            #pragma unroll
            for (int g = 0; g < 2; ++g) {
                u32x4 q = { pk2(cf[4*g+0].x, cf[4*g+0].y), pk2(cf[4*g+1].x, cf[4*g+1].y),
                            pk2(cf[4*g+2].x, cf[4*g+2].y), pk2(cf[4*g+3].x, cf[4*g+3].y) };
                *(u32x4*)(myrow + ((g ^ sw) << 4)) = q;
            }
        }
        {   // pos feat from tables -> groups 2,3
            const f32x4* tx = (const f32x4*)((const float*)(wsb + TX_OFF) + pxc * 16);
            const f32x4* ty = (const f32x4*)((const float*)(wsb + TY_OFF) + pyc * 16);
            const f32x4 z4 = {0.f, 0.f, 0.f, 0.f};
            #pragma unroll
            for (int g = 0; g < 2; ++g) {
                f32x4 u0 = __builtin_elementwise_max(tx[2*g]   + ty[2*g],   z4);
                f32x4 u1 = __builtin_elementwise_max(tx[2*g+1] + ty[2*g+1], z4);
                u32x4 q = { pk2(u0.x, u0.y), pk2(u0.z, u0.w), pk2(u1.x, u1.y), pk2(u1.z, u1.w) };
                *(u32x4*)(myrow + (((2 + g) ^ sw) << 4)) = q;
            }
        }
        {   // time feat (6->16) -> groups 4,5
            const float st[6] = { s2pi(c0), c2pi(c0), s2pi(2.f * c0), c2pi(2.f * c0), s2pi(3.f * c0), c2pi(3.f * c0) };
            const f32x2* Wt2 = (const f32x2*)Wt;
            const f32x2* bt2 = (const f32x2*)bt;
            f32x2 tf[8];
            #pragma unroll
            for (int jp = 0; jp < 8; ++jp) tf[jp] = bt2[jp];
            #pragma unroll
            for (int k = 0; k < 6; ++k) {
                const f32x2 s = mk2(st[k], st[k]);
                #pragma unroll
                for (int jp = 0; jp < 8; ++jp)
                    tf[jp] = __builtin_elementwise_fma(s, Wt2[k * 8 + jp], tf[jp]);
            }
            #pragma unroll
            for (int jp = 0; jp < 8; ++jp) tf[jp] = __builtin_elementwise_max(tf[jp], mk2(0.f, 0.f));
            #pragma unroll
            for (int g = 0; g < 2; ++g) {
                u32x4 q = { pk2(tf[4*g+0].x, tf[4*g+0].y), pk2(tf[4*g+1].x, tf[4*g+1].y),
                            pk2(tf[4*g+2].x, tf[4*g+2].y), pk2(tf[4*g+3].x, tf[4*g+3].y) };
                *(u32x4*)(myrow + (((4 + g) ^ sw) << 4)) = q;
            }
        }
        {   // main_in tail -> groups 6,7 (feature 58 = 1.0 -> bias row of WB)
            u32x4 q6 = { pk2(lat.x, lat.y), pk2(lat.z, lat.w),
                         pk2(xf, yf),       pk2(sxv.x, syv.x) };
            *(u32x4*)(myrow + ((6 ^ sw) << 4)) = q6;
            u32x4 q7 = { pk2(sxv.y, syv.y), pk2(1.0f, 0.f), 0u, 0u };
            *(u32x4*)(myrow + ((7 ^ sw) << 4)) = q7;
        }
    }
    CFENCE();   // same-wave DS in-order: no HW wait needed

    // ================= phase 2: transposed-MFMA pipeline (wave-private) ======
    const int lane = tid & 63, wv = tid >> 6;
    const int cl = lane & 15, lg = lane >> 4;
    const bf16x8* WBf = (const bf16x8*)ws;

    const f32x4 z4 = {0.f, 0.f, 0.f, 0.f};
    unsigned char* wbase = &smem[(wv * 64) * 128];   // this wave's 8 KB region

    // ---- preload ALL A fragments; featL region then dead -> hT aliases it ----
    bf16x8 A0[4], A1[4];
    #pragma unroll
    for (int mt = 0; mt < 4; ++mt) {
        const int rowA = wv * 64 + mt * 16 + cl;
        A0[mt] = *(const bf16x8*)(&smem[rowA * 128 + (((0 + lg) ^ (rowA & 7)) << 4)]);
        A1[mt] = *(const bf16x8*)(&smem[rowA * 128 + (((4 + lg) ^ (rowA & 7)) << 4)]);
    }
    CFENCE();

    // ---- hoist GEMM2 weight fragments (reused 4x each; GEMM3 weights and
    // bias vectors are loaded in-loop to fit the register budget) ----
    bf16x8 W1f[8];
    #pragma unroll
    for (int q = 0; q < 8; ++q) W1f[q] = WBf[1536 + q * 64 + lane];

    // store base for transposed D: point=cl row, hidden byte (lg&1)*8 sub-slot
    const int wrb = cl * 128 + ((lg & 1) << 3);

    // ---- GEMM1: n-outer (6 B-frags loaded once per n), mt-inner; W as A ----
    #pragma unroll 1
    for (int n = 0; n < 4; ++n) {
        const bf16x8 bg0 = WBf[(n * 2 + 0) * 64 + lane];
        const bf16x8 bg1 = WBf[(n * 2 + 1) * 64 + lane];
        const bf16x8 bb0 = WBf[((4 + n) * 2 + 0) * 64 + lane];
        const bf16x8 bb1 = WBf[((4 + n) * 2 + 1) * 64 + lane];
        const bf16x8 bh0 = WBf[((8 + n) * 2 + 0) * 64 + lane];
        const bf16x8 bh1 = WBf[((8 + n) * 2 + 1) * 64 + lane];
        const int gsw = (((2 * n) + (lg >> 1)) ^ (cl & 7)) << 4;   // swizzled granule
        #pragma unroll
        for (int mt = 0; mt < 4; ++mt) {
            f32x4 cg = MFMA(bg0, A0[mt], z4); cg = MFMA(bg1, A1[mt], cg);
            f32x4 cb = MFMA(bb0, A0[mt], z4); cb = MFMA(bb1, A1[mt], cb);
            f32x4 ch = MFMA(bh0, A0[mt], z4); ch = MFMA(bh1, A1[mt], ch);
            f32x2 x01 = __builtin_elementwise_fma(mk2(cg[0], cg[1]), mk2(ch[0], ch[1]), mk2(cb[0], cb[1]));
            f32x2 x23 = __builtin_elementwise_fma(mk2(cg[2], cg[3]), mk2(ch[2], ch[3]), mk2(cb[2], cb[3]));
            f32x2 q01 = gelu2(x01), q23 = gelu2(x23);
            u32x2 d = { pk2(q01.x, q01.y), pk2(q23.x, q23.y) };   // hidden lg*4+0..3
            *(u32x2*)(&(wbase + mt * 2048)[wrb + gsw]) = d;       // one b64 store
        }
    }
    CFENCE();

    // ---- GEMM2: all mt; h as B operand (reads unchanged, proven layout).
    // bias loaded per (mt,n) from b1 (256 B, L1-resident, rematerializable) ----
    #pragma unroll 1
    for (int mt = 0; mt < 4; ++mt) {
        unsigned char* hTm = wbase + mt * 2048;
        bf16x8 h0f = *(const bf16x8*)(&hTm[cl * 128 + (((0 + lg) ^ (cl & 7)) << 4)]);
        bf16x8 h1f = *(const bf16x8*)(&hTm[cl * 128 + (((4 + lg) ^ (cl & 7)) << 4)]);
        #pragma unroll
        for (int n = 0; n < 4; ++n) {
            const f32x4 bw1 = *(const f32x4*)(b1 + n * 16 + lg * 4);
            f32x4 c = MFMA(W1f[n * 2 + 0], h0f, bw1);
            c = MFMA(W1f[n * 2 + 1], h1f, c);
            f32x2 q01 = gelu2(mk2(c[0], c[1])), q23 = gelu2(mk2(c[2], c[3]));
            u32x2 d = { pk2(q01.x, q01.y), pk2(q23.x, q23.y) };
            const int gsw = (((2 * n) + (lg >> 1)) ^ (cl & 7)) << 4;
            *(u32x2*)(&hTm[wrb + gsw]) = d;
        }
    }
    CFENCE();

    // ---- GEMM3: all mt; weights + bias loaded in-loop (cold, 1 KB, L2/L1).
    // D[channel][point] -> lg==0 lane stores 4 channels of point cl ----
    const int pbase = blockIdx.x * 256 + wv * 64;
    #pragma unroll 1
    for (int mt = 0; mt < 4; ++mt) {
        unsigned char* hTm = wbase + mt * 2048;
        bf16x8 g0f = *(const bf16x8*)(&hTm[cl * 128 + (((0 + lg) ^ (cl & 7)) << 4)]);
        bf16x8 g1f = *(const bf16x8*)(&hTm[cl * 128 + (((4 + lg) ^ (cl & 7)) << 4)]);
        const bf16x8 w2a = WBf[2048 + lane];
        const bf16x8 w2b = WBf[2048 + 64 + lane];
        f32x4 bOv = z4;
        if (lg == 0) bOv = *(const f32x4*)b2;
        f32x4 c3 = MFMA(w2a, g0f, bOv);
        c3 = MFMA(w2b, g1f, c3);

        if (lg == 0) {
            f32x4 o;
            #pragma unroll
            for (int r = 0; r < 4; ++r) {
                const float e = __builtin_amdgcn_exp2f(c3[r] * -1.44269504f);
                o[r] = __builtin_amdgcn_rcpf(1.f + e);
            }
            *(f32x4*)(out + (pbase + mt * 16 + cl) * 4) = o;
        }
    }
}

extern "C" void kernel_launch(void* const* d_in, const int* in_sizes, int n_in,
                              void* d_out, int out_size, void* d_ws, size_t ws_size,
                              hipStream_t stream) {
    const int*   rawpos  = (const int*)  d_in[0];
    const float* control = (const float*)d_in[1];
    const float* latent  = (const float*)d_in[2];
    const float* Wc = (const float*)d_in[3];
    const float* bc = (const float*)d_in[4];
    const float* Wt = (const float*)d_in[5];
    const float* bt = (const float*)d_in[6];
    const float* Wp = (const float*)d_in[7];
    const float* bp = (const float*)d_in[8];
    const float* Wf = (const float*)d_in[9];
    const float* bf = (const float*)d_in[10];
    const float* W0 = (const float*)d_in[11];
    const float* b0 = (const float*)d_in[12];
    const float* W1 = (const float*)d_in[13];
    const float* b1 = (const float*)d_in[14];
    const float* W2 = (const float*)d_in[15];
    const float* b2 = (const float*)d_in[16];

    unsigned short* ws = (unsigned short*)d_ws;
    prepack<<<(PREP_ITEMS + 255) / 256, 256, 0, stream>>>(Wf, W0, W1, W2, Wp, bp, bf, b0, ws);
    vfx_fwd<<<NPTS / 256, 256, 0, stream>>>(rawpos, control, latent,
                                            Wc, bc, Wt, bt,
                                            b1, b2, ws, (float*)d_out);
}

// Round 13
// 141.616 us; speedup vs baseline: 1.2072x; 1.2072x over previous
//
#include <hip/hip_runtime.h>
#include <hip/hip_bf16.h>
#include <math.h>

#define NPTS 2097152
#define IMGW 1024
#define IMGH 1024

typedef __attribute__((ext_vector_type(8))) short bf16x8;   // 8 bf16 = 4 VGPR
typedef __attribute__((ext_vector_type(4))) float f32x4;
typedef __attribute__((ext_vector_type(2))) float f32x2;
typedef __attribute__((ext_vector_type(2))) unsigned int u32x2;
typedef __attribute__((ext_vector_type(4))) unsigned int u32x4;

// ws layout (bytes):
//   [0,      34816)  weight frags (17408 ushorts):
//       [0, 12288)     WB: fused [Wf(48xk) ; W0(10xk) ; bias row 58] -> K=64, N=192.
//                      12 ntiles x 2 ksteps x 64 lanes x 8 bf16 fragments.
//                      ntile 0..3 = gamma, 4..7 = beta, 8..11 = h0 cols.
//                      Row 58 holds bff/b0 (feature 58 == 1.0 in phase 1).
//       [12288,16384)  W1: 4 ntiles x 2 ksteps x 64 x 8
//       [16384,17408)  W2: 1 ntile  x 2 ksteps x 64 x 8  (cols 4..15 zero)
//   [34816, 100352)  tX: f32[1024][16]  = Wp_x @ spiral_x(px)          (64 KB)
//   [100352,165888)  tY: f32[1024][16]  = Wp_y @ spiral_y(py) + bp     (64 KB)
//   [165888,174080)  tS: float2[1024]   = {sin(2pi p/1024), sin(4pi p/1024)}
// Requires ws_size >= 174080 bytes.
#define TX_OFF 34816
#define TY_OFF 100352
#define TS_OFF 165888
#define PREP_ITEMS 51200   // 17408 + 16384 + 16384 + 1024

__device__ __forceinline__ unsigned short f2bf(float f) {
    __hip_bfloat16 h = __float2bfloat16(f);          // RTNE; pairs fuse to v_cvt_pk_bf16_f32
    return __builtin_bit_cast(unsigned short, h);
}
__device__ __forceinline__ unsigned pk2(float a, float b) {
    return (unsigned)f2bf(a) | ((unsigned)f2bf(b) << 16);
}
__device__ __forceinline__ f32x2 mk2(float a, float b) { f32x2 r; r.x = a; r.y = b; return r; }

__device__ __forceinline__ float s2pi(float r) { r = r - floorf(r); return __builtin_amdgcn_sinf(r); }
__device__ __forceinline__ float c2pi(float r) { r = r + 0.25f; r = r - floorf(r); return __builtin_amdgcn_sinf(r); }

__global__ __launch_bounds__(256) void prepack(
    const float* __restrict__ Wf, const float* __restrict__ W0,
    const float* __restrict__ W1, const float* __restrict__ W2,
    const float* __restrict__ Wp, const float* __restrict__ bp,
    const float* __restrict__ bff, const float* __restrict__ b0,
    unsigned short* __restrict__ ws)
{
    int idx = blockIdx.x * 256 + threadIdx.x;
    if (idx < 17408) {                           // ---- weight fragments ----
        float val = 0.f;
        if (idx < 12288) {                       // fused Wf|W0 -> B frags (K=64)
            int e = idx, i = e & 7, l = (e >> 3) & 63, ks = (e >> 9) & 1, n = e >> 10;
            int k = ks * 32 + (l >> 4) * 8 + i;
            int c16 = l & 15;
            if (n < 8) {
                if (k < 48) val = Wf[k * 128 + n * 16 + c16];
                else if (k == 58) val = bff[n * 16 + c16];           // bias row
            } else {
                if (k >= 48 && k < 58) val = W0[(k - 48) * 64 + (n - 8) * 16 + c16];
                else if (k == 58) val = b0[(n - 8) * 16 + c16];      // bias row
            }
        } else if (idx < 16384) {                // W1 (64x64)
            int e = idx - 12288, i = e & 7, l = (e >> 3) & 63, ks = (e >> 9) & 1, n = e >> 10;
            int k = ks * 32 + (l >> 4) * 8 + i;
            val = W1[k * 64 + n * 16 + (l & 15)];
        } else {                                 // W2 (64x4, N padded to 16)
            int e = idx - 16384, i = e & 7, l = (e >> 3) & 63, ks = (e >> 9) & 1;
            int k = ks * 32 + (l >> 4) * 8 + i;
            int c = l & 15;
            if (c < 4) val = W2[k * 4 + c];
        }
        ws[idx] = f2bf(val);
    } else if (idx < 33792) {                    // ---- tX ----
        int e = idx - 17408, p = e >> 4, j = e & 15;
        float xf = (float)p * (1.0f / IMGW);
        float s[6] = { s2pi(xf), c2pi(xf), s2pi(2.f * xf), c2pi(2.f * xf), s2pi(3.f * xf), c2pi(3.f * xf) };
        float a = 0.f;
        #pragma unroll
        for (int k = 0; k < 6; ++k) a = fmaf(s[k], Wp[k * 16 + j], a);
        ((float*)((char*)ws + TX_OFF))[p * 16 + j] = a;
    } else if (idx < 50176) {                    // ---- tY (bias folded) ----
        int e = idx - 33792, p = e >> 4, j = e & 15;
        float yf = (float)p * (1.0f / IMGH);
        float s[6] = { s2pi(yf), c2pi(yf), s2pi(2.f * yf), c2pi(2.f * yf), s2pi(3.f * yf), c2pi(3.f * yf) };
        float a = bp[j];
        #pragma unroll
        for (int k = 0; k < 6; ++k) a = fmaf(s[k], Wp[(6 + k) * 16 + j], a);
        ((float*)((char*)ws + TY_OFF))[p * 16 + j] = a;
    } else if (idx < 51200) {                    // ---- tS ----
        int p = idx - 50176;
        float xf = (float)p * (1.0f / IMGW);
        float2 v; v.x = s2pi(xf); v.y = s2pi(2.f * xf);
        ((float2*)((char*)ws + TS_OFF))[p] = v;
    }
}

// R10's tanh-form GELU (harness-proven): 5 VALU + 2 TRANS per element.
//   x2 = x*x;  m = fma(x2, -K2, -K);  e = exp2(x*m);  s = rcp(1+e);  out = x*s
// K = 2*sqrt(2/pi)*log2(e) = 2.30220818, K2 = K*0.044715 = 0.10294324.
// Max deviation from exact erf-GELU ~4e-4, well under the 1.41e-2 threshold.
__device__ __forceinline__ f32x2 gelu2(f32x2 x) {
    const f32x2 x2 = x * x;
    f32x2 m = __builtin_elementwise_fma(x2, mk2(-0.10294324f, -0.10294324f),
                                        mk2(-2.30220818f, -2.30220818f));
    f32x2 a = x * m;
    f32x2 e; e.x = __builtin_amdgcn_exp2f(a.x); e.y = __builtin_amdgcn_exp2f(a.y);
    f32x2 s; s.x = __builtin_amdgcn_rcpf(1.f + e.x); s.y = __builtin_amdgcn_rcpf(1.f + e.y);
    return x * s;
}

#define MFMA(a, b, c) __builtin_amdgcn_mfma_f32_16x16x32_bf16((a), (b), (c), 0, 0, 0)

// Compiler-only reorder fence (R7: wave-private LDS + in-order DS pipe ->
// no hardware lgkmcnt drains needed; compiler auto-inserts data-dep waits).
#define CFENCE() asm volatile("" ::: "memory")

// TRANSPOSED MFMA structure (R9, harness-proven): W as A-operand, feat/h as
// B-operand -> D^T: lane holds point=cl, hidden=lg*4+r. One ds_write_b64 per
// (n,mt); GEMM3 stores one dwordx4 per point from lg==0 lanes.
// LDS: featL = 256 rows x 64 bf16 (XOR-swizzled 16B granules) = 32 KB; hT
// tiles alias the wave's own featL rows (dead after A-fragment preload).
// Wave-private everywhere -> NO __syncthreads.
//
// Operating point: __launch_bounds__(256,4) — R11's proven optimum (VGPR 60,
// 41% occupancy, no spill, 142 us). R12 measured (256,5): the ~102-total-reg
// budget spills (WRITE_SIZE 32MB->221MB, +29 us) and occupancy does NOT rise;
// de-hoisting W1f to fit is EV-neutral (L2 refetch cost ~= occupancy gain,
// calibrated on R6/R11 measurements). Occupancy lever exhausted here.
__global__ __launch_bounds__(256, 4) void vfx_fwd(
    const int* __restrict__ rawpos, const float* __restrict__ control,
    const float* __restrict__ latent,
    const float* __restrict__ Wc, const float* __restrict__ bc,
    const float* __restrict__ Wt, const float* __restrict__ bt,
    const float* __restrict__ b1, const float* __restrict__ b2,
    const unsigned short* __restrict__ ws, float* __restrict__ out)
{
    __shared__ __align__(16) unsigned char smem[32768];
    const int tid = threadIdx.x;
    const int i = blockIdx.x * 256 + tid;
    const unsigned char* wsb = (const unsigned char*)ws;

    // ============ phase 1: per-point features -> LDS (proven code) ====
    {
        const int px = rawpos[2 * i], py = rawpos[2 * i + 1];
        const float c0 = control[2 * i], c1 = control[2 * i + 1];
        const float4 lat = *reinterpret_cast<const float4*>(latent + 4 * (py * IMGW + px));
        const int pxc = min(max(px, 0), IMGW - 1), pyc = min(max(py, 0), IMGH - 1);
        const float xf = (float)pxc * (1.0f / IMGW);
        const float yf = (float)pyc * (1.0f / IMGH);
        const float2 sxv = ((const float2*)(wsb + TS_OFF))[pxc];
        const float2 syv = ((const float2*)(wsb + TS_OFF))[pyc];

        unsigned char* myrow = &smem[tid * 128];
        const int sw = tid & 7;

        {   // control feat (2->16) -> groups 0,1
            const f32x2* Wc2 = (const f32x2*)Wc;
            const f32x2* bc2 = (const f32x2*)bc;
            const f32x2 c0s = mk2(c0, c0), c1s = mk2(c1, c1);
            f32x2 cf[8];
            #pragma unroll
            for (int jp = 0; jp < 8; ++jp) {
                f32x2 a = __builtin_elementwise_fma(c1s, Wc2[8 + jp], bc2[jp]);
                a = __builtin_elementwise_fma(c0s, Wc2[jp], a);
                cf[jp] = __builtin_elementwise_max(a, mk2(0.f, 0.f));
            }
            #pragma unroll
            for (int g = 0; g < 2; ++g) {
                u32x4 q = { pk2(cf[4*g+0].x, cf[4*g+0].y), pk2(cf[4*g+1].x, cf[4*g+1].y),
                            pk2(cf[4*g+2].x, cf[4*g+2].y), pk2(cf[4*g+3].x, cf[4*g+3].y) };
                *(u32x4*)(myrow + ((g ^ sw) << 4)) = q;
            }
        }
        {   // pos feat from tables -> groups 2,3
            const f32x4* tx = (const f32x4*)((const float*)(wsb + TX_OFF) + pxc * 16);
            const f32x4* ty = (const f32x4*)((const float*)(wsb + TY_OFF) + pyc * 16);
            const f32x4 z4 = {0.f, 0.f, 0.f, 0.f};
            #pragma unroll
            for (int g = 0; g < 2; ++g) {
                f32x4 u0 = __builtin_elementwise_max(tx[2*g]   + ty[2*g],   z4);
                f32x4 u1 = __builtin_elementwise_max(tx[2*g+1] + ty[2*g+1], z4);
                u32x4 q = { pk2(u0.x, u0.y), pk2(u0.z, u0.w), pk2(u1.x, u1.y), pk2(u1.z, u1.w) };
                *(u32x4*)(myrow + (((2 + g) ^ sw) << 4)) = q;
            }
        }
        {   // time feat (6->16) -> groups 4,5
            const float st[6] = { s2pi(c0), c2pi(c0), s2pi(2.f * c0), c2pi(2.f * c0), s2pi(3.f * c0), c2pi(3.f * c0) };
            const f32x2* Wt2 = (const f32x2*)Wt;
            const f32x2* bt2 = (const f32x2*)bt;
            f32x2 tf[8];
            #pragma unroll
            for (int jp = 0; jp < 8; ++jp) tf[jp] = bt2[jp];
            #pragma unroll
            for (int k = 0; k < 6; ++k) {
                const f32x2 s = mk2(st[k], st[k]);
                #pragma unroll
                for (int jp = 0; jp < 8; ++jp)
                    tf[jp] = __builtin_elementwise_fma(s, Wt2[k * 8 + jp], tf[jp]);
            }
            #pragma unroll
            for (int jp = 0; jp < 8; ++jp) tf[jp] = __builtin_elementwise_max(tf[jp], mk2(0.f, 0.f));
            #pragma unroll
            for (int g = 0; g < 2; ++g) {
                u32x4 q = { pk2(tf[4*g+0].x, tf[4*g+0].y), pk2(tf[4*g+1].x, tf[4*g+1].y),
                            pk2(tf[4*g+2].x, tf[4*g+2].y), pk2(tf[4*g+3].x, tf[4*g+3].y) };
                *(u32x4*)(myrow + (((4 + g) ^ sw) << 4)) = q;
            }
        }
        {   // main_in tail -> groups 6,7 (feature 58 = 1.0 -> bias row of WB)
            u32x4 q6 = { pk2(lat.x, lat.y), pk2(lat.z, lat.w),
                         pk2(xf, yf),       pk2(sxv.x, syv.x) };
            *(u32x4*)(myrow + ((6 ^ sw) << 4)) = q6;
            u32x4 q7 = { pk2(sxv.y, syv.y), pk2(1.0f, 0.f), 0u, 0u };
            *(u32x4*)(myrow + ((7 ^ sw) << 4)) = q7;
        }
    }
    CFENCE();   // same-wave DS in-order: no HW wait needed

    // ================= phase 2: transposed-MFMA pipeline (wave-private) ======
    const int lane = tid & 63, wv = tid >> 6;
    const int cl = lane & 15, lg = lane >> 4;
    const bf16x8* WBf = (const bf16x8*)ws;

    const f32x4 z4 = {0.f, 0.f, 0.f, 0.f};
    unsigned char* wbase = &smem[(wv * 64) * 128];   // this wave's 8 KB region

    // ---- preload ALL A fragments; featL region then dead -> hT aliases it ----
    bf16x8 A0[4], A1[4];
    #pragma unroll
    for (int mt = 0; mt < 4; ++mt) {
        const int rowA = wv * 64 + mt * 16 + cl;
        A0[mt] = *(const bf16x8*)(&smem[rowA * 128 + (((0 + lg) ^ (rowA & 7)) << 4)]);
        A1[mt] = *(const bf16x8*)(&smem[rowA * 128 + (((4 + lg) ^ (rowA & 7)) << 4)]);
    }
    CFENCE();

    // ---- hoist GEMM2 weight fragments (reused 4x each; GEMM3 weights and
    // bias vectors are loaded in-loop to fit the register budget) ----
    bf16x8 W1f[8];
    #pragma unroll
    for (int q = 0; q < 8; ++q) W1f[q] = WBf[1536 + q * 64 + lane];

    // store base for transposed D: point=cl row, hidden byte (lg&1)*8 sub-slot
    const int wrb = cl * 128 + ((lg & 1) << 3);

    // ---- GEMM1: n-outer (6 B-frags loaded once per n), mt-inner; W as A ----
    #pragma unroll 1
    for (int n = 0; n < 4; ++n) {
        const bf16x8 bg0 = WBf[(n * 2 + 0) * 64 + lane];
        const bf16x8 bg1 = WBf[(n * 2 + 1) * 64 + lane];
        const bf16x8 bb0 = WBf[((4 + n) * 2 + 0) * 64 + lane];
        const bf16x8 bb1 = WBf[((4 + n) * 2 + 1) * 64 + lane];
        const bf16x8 bh0 = WBf[((8 + n) * 2 + 0) * 64 + lane];
        const bf16x8 bh1 = WBf[((8 + n) * 2 + 1) * 64 + lane];
        const int gsw = (((2 * n) + (lg >> 1)) ^ (cl & 7)) << 4;   // swizzled granule
        #pragma unroll
        for (int mt = 0; mt < 4; ++mt) {
            f32x4 cg = MFMA(bg0, A0[mt], z4); cg = MFMA(bg1, A1[mt], cg);
            f32x4 cb = MFMA(bb0, A0[mt], z4); cb = MFMA(bb1, A1[mt], cb);
            f32x4 ch = MFMA(bh0, A0[mt], z4); ch = MFMA(bh1, A1[mt], ch);
            f32x2 x01 = __builtin_elementwise_fma(mk2(cg[0], cg[1]), mk2(ch[0], ch[1]), mk2(cb[0], cb[1]));
            f32x2 x23 = __builtin_elementwise_fma(mk2(cg[2], cg[3]), mk2(ch[2], ch[3]), mk2(cb[2], cb[3]));
            f32x2 q01 = gelu2(x01), q23 = gelu2(x23);
            u32x2 d = { pk2(q01.x, q01.y), pk2(q23.x, q23.y) };   // hidden lg*4+0..3
            *(u32x2*)(&(wbase + mt * 2048)[wrb + gsw]) = d;       // one b64 store
        }
    }
    CFENCE();

    // ---- GEMM2: all mt; h as B operand (reads unchanged, proven layout).
    // bias loaded per (mt,n) from b1 (256 B, L1-resident, rematerializable) ----
    #pragma unroll 1
    for (int mt = 0; mt < 4; ++mt) {
        unsigned char* hTm = wbase + mt * 2048;
        bf16x8 h0f = *(const bf16x8*)(&hTm[cl * 128 + (((0 + lg) ^ (cl & 7)) << 4)]);
        bf16x8 h1f = *(const bf16x8*)(&hTm[cl * 128 + (((4 + lg) ^ (cl & 7)) << 4)]);
        #pragma unroll
        for (int n = 0; n < 4; ++n) {
            const f32x4 bw1 = *(const f32x4*)(b1 + n * 16 + lg * 4);
            f32x4 c = MFMA(W1f[n * 2 + 0], h0f, bw1);
            c = MFMA(W1f[n * 2 + 1], h1f, c);
            f32x2 q01 = gelu2(mk2(c[0], c[1])), q23 = gelu2(mk2(c[2], c[3]));
            u32x2 d = { pk2(q01.x, q01.y), pk2(q23.x, q23.y) };
            const int gsw = (((2 * n) + (lg >> 1)) ^ (cl & 7)) << 4;
            *(u32x2*)(&hTm[wrb + gsw]) = d;
        }
    }
    CFENCE();

    // ---- GEMM3: all mt; weights + bias loaded in-loop (cold, 1 KB, L2/L1).
    // D[channel][point] -> lg==0 lane stores 4 channels of point cl ----
    const int pbase = blockIdx.x * 256 + wv * 64;
    #pragma unroll 1
    for (int mt = 0; mt < 4; ++mt) {
        unsigned char* hTm = wbase + mt * 2048;
        bf16x8 g0f = *(const bf16x8*)(&hTm[cl * 128 + (((0 + lg) ^ (cl & 7)) << 4)]);
        bf16x8 g1f = *(const bf16x8*)(&hTm[cl * 128 + (((4 + lg) ^ (cl & 7)) << 4)]);
        const bf16x8 w2a = WBf[2048 + lane];
        const bf16x8 w2b = WBf[2048 + 64 + lane];
        f32x4 bOv = z4;
        if (lg == 0) bOv = *(const f32x4*)b2;
        f32x4 c3 = MFMA(w2a, g0f, bOv);
        c3 = MFMA(w2b, g1f, c3);

        if (lg == 0) {
            f32x4 o;
            #pragma unroll
            for (int r = 0; r < 4; ++r) {
                const float e = __builtin_amdgcn_exp2f(c3[r] * -1.44269504f);
                o[r] = __builtin_amdgcn_rcpf(1.f + e);
            }
            *(f32x4*)(out + (pbase + mt * 16 + cl) * 4) = o;
        }
    }
}

extern "C" void kernel_launch(void* const* d_in, const int* in_sizes, int n_in,
                              void* d_out, int out_size, void* d_ws, size_t ws_size,
                              hipStream_t stream) {
    const int*   rawpos  = (const int*)  d_in[0];
    const float* control = (const float*)d_in[1];
    const float* latent  = (const float*)d_in[2];
    const float* Wc = (const float*)d_in[3];
    const float* bc = (const float*)d_in[4];
    const float* Wt = (const float*)d_in[5];
    const float* bt = (const float*)d_in[6];
    const float* Wp = (const float*)d_in[7];
    const float* bp = (const float*)d_in[8];
    const float* Wf = (const float*)d_in[9];
    const float* bf = (const float*)d_in[10];
    const float* W0 = (const float*)d_in[11];
    const float* b0 = (const float*)d_in[12];
    const float* W1 = (const float*)d_in[13];
    const float* b1 = (const float*)d_in[14];
    const float* W2 = (const float*)d_in[15];
    const float* b2 = (const float*)d_in[16];

    unsigned short* ws = (unsigned short*)d_ws;
    prepack<<<(PREP_ITEMS + 255) / 256, 256, 0, stream>>>(Wf, W0, W1, W2, Wp, bp, bf, b0, ws);
    vfx_fwd<<<NPTS / 256, 256, 0, stream>>>(rawpos, control, latent,
                                            Wc, bc, Wt, bt,
                                            b1, b2, ws, (float*)d_out);
}